// Round 2
// baseline (236.522 us; speedup 1.0000x reference)
//
#include <hip/hip_runtime.h>

// Problem constants: org/enh [32,3,512,512] fp32.
#define PH 128                       // pooled H (512/4)
#define PW 128                       // pooled W
#define NPOOL   (32 * PH * PW)       // 524288 pooled elements
#define NPLANE  96                   // 32 b x 3 c planes
#define PLANE_F4 65536               // 512 rows x 128 float4 per (b,c) plane
#define ROWS_PB 8                    // image rows per block (2 pooled rows)
#define RG_PER_PLANE 64              // 512 / 8
#define NBLK_A  (NPLANE * RG_PER_PLANE)   // 6144 blocks
#define NBLK_B  (NPOOL / 256)             // 2048 blocks
#define INV48   (1.0f / 48.0f)       // /3 channels /16 pool window

typedef float vf4 __attribute__((ext_vector_type(4)));

__device__ __forceinline__ float hsum(vf4 d) {
    return (d.x + d.y) + (d.z + d.w);
}

// Stage A: per-(b,c)-plane fused 4x4 avgpool of (org - enh).
// One block = one plane x 8 contiguous image rows -> each tensor read is a
// single contiguous 16 KB span (every wave-load = sequential 1 KB). This is
// the DRAM-page-friendly shape; R0 read 1KB chunks at 2KB stride (3.66 TB/s),
// R1 read 24 scattered chunks over 6MB (regressed). Plain loads (no
// nontemporal) to rule the NT hint out of the read-BW ceiling.
// ~50 VGPR + 4 KB LDS -> 8 blocks/CU = 32 waves/CU (full occupancy vs R0's ~16).
__global__ __launch_bounds__(256) void stageA_pool_kernel(
    const vf4* __restrict__ o4, const vf4* __restrict__ e4,
    float* __restrict__ partial, float* __restrict__ out)
{
    if (blockIdx.x == 0 && threadIdx.x == 0) out[0] = 0.f;  // for stage B atomics

    const int t  = threadIdx.x;
    const int p  = blockIdx.x >> 6;        // (b,c) plane, 0..95
    const int rg = blockIdx.x & 63;        // row-group: image rows 8rg..8rg+7
    const int base = p * PLANE_F4 + rg * (ROWS_PB * 128);

    // 8 independent contiguous wave-loads, all in flight before first use.
    vf4 o0 = o4[base +         t];
    vf4 o1 = o4[base + 256  +  t];
    vf4 o2 = o4[base + 512  +  t];
    vf4 o3 = o4[base + 768  +  t];
    vf4 e0 = e4[base +         t];
    vf4 e1 = e4[base + 256  +  t];
    vf4 e2 = e4[base + 512  +  t];
    vf4 e3 = e4[base + 768  +  t];

    // Tile element i = j*256 + t  ->  tile row i>>7 = 2j + (t>>7), col t&127.
    __shared__ float lds[ROWS_PB][128];
    const int r0 = t >> 7;                 // 0 or 1
    const int c  = t & 127;
    lds[r0 + 0][c] = hsum(o0 - e0);
    lds[r0 + 2][c] = hsum(o1 - e1);
    lds[r0 + 4][c] = hsum(o2 - e2);
    lds[r0 + 6][c] = hsum(o3 - e3);
    __syncthreads();

    // 2 pooled rows x 128 cols = 256 outputs = 1 per thread.
    const int yp = t >> 7;                 // 0 or 1
    const int x  = t & 127;
    float v = (lds[4 * yp + 0][x] + lds[4 * yp + 1][x])
            + (lds[4 * yp + 2][x] + lds[4 * yp + 3][x]);
    partial[p * (PH * PW) + (rg * 2 + yp) * PW + x] = v * INV48;
}

// Stage B: shift-difference sum-of-squares with inline channel-plane sum
// (R0's proven 15-tap form; 6 MB working set, L2/L3-resident), block-reduce,
// one device-scope atomicAdd per block (folds the old 3rd dispatch away).
__global__ __launch_bounds__(256) void spa_reduce_kernel(
    const float* __restrict__ partial, float* __restrict__ out)
{
    int idx = blockIdx.x * 256 + threadIdx.x;
    int pw = idx & (PW - 1);
    int ph = (idx >> 7) & (PH - 1);
    int b  = idx >> 14;

    const float* p0 = partial + (b * 3 + 0) * (PH * PW);
    const float* p1 = partial + (b * 3 + 1) * (PH * PW);
    const float* p2 = partial + (b * 3 + 2) * (PH * PW);

    #define POOLED(y, x) (p0[(y) * PW + (x)] + p1[(y) * PW + (x)] + p2[(y) * PW + (x)])
    float cc = POOLED(ph, pw);
    float l  = (pw > 0)      ? POOLED(ph, pw - 1) : 0.f;
    float r  = (pw < PW - 1) ? POOLED(ph, pw + 1) : 0.f;
    float u  = (ph > 0)      ? POOLED(ph - 1, pw) : 0.f;
    float d  = (ph < PH - 1) ? POOLED(ph + 1, pw) : 0.f;
    #undef POOLED

    float dl = cc - l, dr = cc - r, du = cc - u, dd = cc - d;
    float s = (dl * dl + dr * dr) + (du * du + dd * dd);

#pragma unroll
    for (int off = 32; off > 0; off >>= 1)
        s += __shfl_down(s, off, 64);

    __shared__ float smem[4];
    int lane = threadIdx.x & 63;
    int wid  = threadIdx.x >> 6;
    if (lane == 0) smem[wid] = s;
    __syncthreads();
    if (threadIdx.x == 0)
        atomicAdd(out, ((smem[0] + smem[1]) + (smem[2] + smem[3]))
                           * (1.0f / (float)NPOOL));
}

extern "C" void kernel_launch(void* const* d_in, const int* in_sizes, int n_in,
                              void* d_out, int out_size, void* d_ws, size_t ws_size,
                              hipStream_t stream) {
    const vf4* o4 = (const vf4*)d_in[0];
    const vf4* e4 = (const vf4*)d_in[1];
    float* out     = (float*)d_out;
    float* partial = (float*)d_ws;     // 6 MB: [96][128][128] per-channel pooled

    stageA_pool_kernel<<<NBLK_A, 256, 0, stream>>>(o4, e4, partial, out);
    spa_reduce_kernel<<<NBLK_B, 256, 0, stream>>>(partial, out);
}

// Round 5
// 220.129 us; speedup vs baseline: 1.0745x; 1.0745x over previous
//
#include <hip/hip_runtime.h>

// Problem constants (from reference): org/enh [32,3,512,512] fp32.
#define NB 32
#define NC 3
#define NH 512
#define NW 512
#define PH 128   // NH/4
#define PW 128   // NW/4
#define NPOOL  (NB * PH * PW)     // 524288 pooled elements
#define NPLANE (NB * NC)          // 96 (b,c) planes
#define PLANE_ELEMS (PH * PW)     // 16384 per partial plane
#define NITEMS (NPLANE * PLANE_ELEMS)  // 1,572,864 stage-A work items
#define NBLK_A 1024
#define ITEMS_A 6                 // 1024*256*6 == NITEMS exactly
#define STRIDE_A (NBLK_A * 256)   // 262144
#define NBLK_RED (NPOOL / 256)    // 2048

typedef float vf4 __attribute__((ext_vector_type(4)));

// item -> float4 base index in a [96][512][128] float4 layout:
// plane = item>>14, pooled row = (item>>7)&127 (covers image rows 4r..4r+3),
// x4 = item&127.
__device__ __forceinline__ int spa_item_base(int item) {
    return ((item >> 14) << 16) + (((item >> 7) & 127) << 9) + (item & 127);
}

// Stage A: per-channel fused 4x4 avgpool of (org - enh), deep software
// pipeline — R0's proven form (~55 us, 3.66 TB/s effective read).
// Evidence R1/R2: one-shot blocks (scattered OR contiguous) both land at
// ~2.7 TB/s; sustained per-thread MLP is the lever, not contiguity. The
// read ceiling is outstanding-miss-slots x 128B / ~580ns latency; this
// 6-deep register double-buffer saturates it.
__global__ __launch_bounds__(256) void spa_pool_a(
    const vf4* __restrict__ o4, const vf4* __restrict__ e4,
    float* __restrict__ partial, float* __restrict__ out)
{
    if (blockIdx.x == 0 && threadIdx.x == 0) out[0] = 0.f;  // for stage B atomics

    int item = blockIdx.x * 256 + threadIdx.x;

    int base = spa_item_base(item);
    vf4 oc0 = __builtin_nontemporal_load(o4 + base);
    vf4 oc1 = __builtin_nontemporal_load(o4 + base + 128);
    vf4 oc2 = __builtin_nontemporal_load(o4 + base + 256);
    vf4 oc3 = __builtin_nontemporal_load(o4 + base + 384);
    vf4 ec0 = __builtin_nontemporal_load(e4 + base);
    vf4 ec1 = __builtin_nontemporal_load(e4 + base + 128);
    vf4 ec2 = __builtin_nontemporal_load(e4 + base + 256);
    vf4 ec3 = __builtin_nontemporal_load(e4 + base + 384);

#pragma unroll
    for (int it = 0; it < ITEMS_A; ++it) {
        vf4 on0, on1, on2, on3, en0, en1, en2, en3;
        if (it < ITEMS_A - 1) {
            int nbase = spa_item_base(item + STRIDE_A);
            on0 = __builtin_nontemporal_load(o4 + nbase);
            on1 = __builtin_nontemporal_load(o4 + nbase + 128);
            on2 = __builtin_nontemporal_load(o4 + nbase + 256);
            on3 = __builtin_nontemporal_load(o4 + nbase + 384);
            en0 = __builtin_nontemporal_load(e4 + nbase);
            en1 = __builtin_nontemporal_load(e4 + nbase + 128);
            en2 = __builtin_nontemporal_load(e4 + nbase + 256);
            en3 = __builtin_nontemporal_load(e4 + nbase + 384);
        }

        vf4 d = ((oc0 - ec0) + (oc1 - ec1)) + ((oc2 - ec2) + (oc3 - ec3));
        float v = (d.x + d.y) + (d.z + d.w);
        partial[item] = v * (1.0f / 48.0f);   // /3 channels /16 pool window

        if (it < ITEMS_A - 1) {
            oc0 = on0; oc1 = on1; oc2 = on2; oc3 = on3;
            ec0 = en0; ec1 = en1; ec2 = en2; ec3 = en3;
            item += STRIDE_A;
        }
    }
}

// Stage B: shift-difference sum-of-squares with inline channel-plane sum
// (proven 15-tap form; 6 MB working set, L2/L3-resident), block-reduce,
// then ONE device-scope atomicAdd per block — replaces the old
// 2048-partial buffer + third dispatch (saves ~4 us kernel + ~2 us gap).
// Atomic-order nondeterminism ~1e-8 relative; validated absmax==0 in R1/R2.
__global__ __launch_bounds__(256) void spa_stencil_b(
    const float* __restrict__ partial, float* __restrict__ out)
{
    int idx = blockIdx.x * blockDim.x + threadIdx.x;
    int pw = idx & (PW - 1);
    int ph = (idx >> 7) & (PH - 1);
    int b  = idx >> 14;

    const float* p0 = partial + (b * 3 + 0) * PLANE_ELEMS;
    const float* p1 = partial + (b * 3 + 1) * PLANE_ELEMS;
    const float* p2 = partial + (b * 3 + 2) * PLANE_ELEMS;

    #define POOLED(y, x) (p0[(y) * PW + (x)] + p1[(y) * PW + (x)] + p2[(y) * PW + (x)])
    float c = POOLED(ph, pw);
    float l = (pw > 0)      ? POOLED(ph, pw - 1) : 0.f;
    float r = (pw < PW - 1) ? POOLED(ph, pw + 1) : 0.f;
    float u = (ph > 0)      ? POOLED(ph - 1, pw) : 0.f;
    float d = (ph < PH - 1) ? POOLED(ph + 1, pw) : 0.f;
    #undef POOLED

    float dl = c - l, dr = c - r, du = c - u, dd = c - d;
    float s = (dl * dl + dr * dr) + (du * du + dd * dd);

#pragma unroll
    for (int off = 32; off > 0; off >>= 1)
        s += __shfl_down(s, off, 64);

    __shared__ float smem[4];
    int lane = threadIdx.x & 63;
    int wid  = threadIdx.x >> 6;
    if (lane == 0) smem[wid] = s;
    __syncthreads();
    if (threadIdx.x == 0)
        atomicAdd(out, ((smem[0] + smem[1]) + (smem[2] + smem[3]))
                           * (1.0f / (float)NPOOL));
}

extern "C" void kernel_launch(void* const* d_in, const int* in_sizes, int n_in,
                              void* d_out, int out_size, void* d_ws, size_t ws_size,
                              hipStream_t stream) {
    const vf4* o4 = (const vf4*)d_in[0];
    const vf4* e4 = (const vf4*)d_in[1];
    float* out     = (float*)d_out;
    float* partial = (float*)d_ws;     // 6 MB: [96][128][128] per-channel pooled

    spa_pool_a<<<NBLK_A, 256, 0, stream>>>(o4, e4, partial, out);
    spa_stencil_b<<<NBLK_RED, 256, 0, stream>>>(partial, out);
}

// Round 6
// 200.872 us; speedup vs baseline: 1.1775x; 1.0959x over previous
//
#include <hip/hip_runtime.h>

// Problem constants (from reference): org/enh [32,3,512,512] fp32.
#define NB 32
#define NC 3
#define PH 128   // 512/4
#define PW 128   // 512/4
#define NPOOL  (NB * PH * PW)     // 524288 pooled pixels
#define NPLANE (NB * NC)          // 96 (b,c) planes
#define NITEMS (NPLANE * PH * PW) // 1,572,864 stage-A work items
#define NBLK_A 1024
#define ITEMS_A 6                 // 1024*256*6 == NITEMS exactly
#define STRIDE_A (NBLK_A * 256)   // 262144
#define NBLK_RED (NPOOL / 256)    // 2048

typedef float vf4 __attribute__((ext_vector_type(4)));

// item -> float4 base index in the [96][512][128]-float4 input layout:
// plane = item>>14, pooled row = (item>>7)&127 (covers image rows 4r..4r+3),
// x4 = item&127.
__device__ __forceinline__ int spa_item_base(int item) {
    return ((item >> 14) << 16) + (((item >> 7) & 127) << 9) + (item & 127);
}

// Stage A: per-channel fused 4x4 avgpool of (org - enh), deep software
// pipeline — R0's proven form (~55 us, 3.66 TB/s effective read; the per-CU
// outstanding-miss-line cap, ~14 B/ns/CU, is the binding limit — R1/R2
// restructures both regressed or tied). LOADS ARE UNCHANGED from R0.
// Only the store changed: channel-interleaved [b][y][x][4] (c in .x/.y/.z,
// .w dead) so stage B needs 5 dwordx4 taps instead of 15 scalar taps.
__global__ __launch_bounds__(256) void spa_pool_a(
    const vf4* __restrict__ o4, const vf4* __restrict__ e4,
    float* __restrict__ pooled4)
{
    int item = blockIdx.x * 256 + threadIdx.x;

    int base = spa_item_base(item);
    vf4 oc0 = __builtin_nontemporal_load(o4 + base);
    vf4 oc1 = __builtin_nontemporal_load(o4 + base + 128);
    vf4 oc2 = __builtin_nontemporal_load(o4 + base + 256);
    vf4 oc3 = __builtin_nontemporal_load(o4 + base + 384);
    vf4 ec0 = __builtin_nontemporal_load(e4 + base);
    vf4 ec1 = __builtin_nontemporal_load(e4 + base + 128);
    vf4 ec2 = __builtin_nontemporal_load(e4 + base + 256);
    vf4 ec3 = __builtin_nontemporal_load(e4 + base + 384);

#pragma unroll
    for (int it = 0; it < ITEMS_A; ++it) {
        vf4 on0, on1, on2, on3, en0, en1, en2, en3;
        if (it < ITEMS_A - 1) {
            int nbase = spa_item_base(item + STRIDE_A);
            on0 = __builtin_nontemporal_load(o4 + nbase);
            on1 = __builtin_nontemporal_load(o4 + nbase + 128);
            on2 = __builtin_nontemporal_load(o4 + nbase + 256);
            on3 = __builtin_nontemporal_load(o4 + nbase + 384);
            en0 = __builtin_nontemporal_load(e4 + nbase);
            en1 = __builtin_nontemporal_load(e4 + nbase + 128);
            en2 = __builtin_nontemporal_load(e4 + nbase + 256);
            en3 = __builtin_nontemporal_load(e4 + nbase + 384);
        }

        vf4 d = ((oc0 - ec0) + (oc1 - ec1)) + ((oc2 - ec2) + (oc3 - ec3));
        float v = (d.x + d.y) + (d.z + d.w);

        // item -> (plane, y, x); plane -> (b = plane/3, c = plane%3).
        int plane = item >> 14;
        int b = plane / 3;
        int c = plane - 3 * b;
        int pix = (b << 14) | (item & 16383);           // (b,y,x) pixel id
        pooled4[(pix << 2) + c] = v * (1.0f / 48.0f);   // /3 channels /16 window

        if (it < ITEMS_A - 1) {
            oc0 = on0; oc1 = on1; oc2 = on2; oc3 = on3;
            ec0 = en0; ec1 = en1; ec2 = en2; ec3 = en3;
            item += STRIDE_A;
        }
    }
}

// Stage B: shift-difference sum-of-squares on the channel-interleaved pooled
// buffer (8 MB, L2/L3-resident): 5 coalesced dwordx4 taps per output pixel
// (was 15 scalar taps over 3 planes). Per-block partial stores — NO
// same-address atomics (R5 measured the 2048-atomic storm at ~+28 us).
__global__ __launch_bounds__(256) void spa_stencil_b(
    const vf4* __restrict__ pooled4, float* __restrict__ partials_out)
{
    int idx = blockIdx.x * 256 + threadIdx.x;
    int x = idx & (PW - 1);
    int y = (idx >> 7) & (PH - 1);
    int b = idx >> 14;
    const vf4* p = pooled4 + (b << 14);

    const vf4 z = {0.f, 0.f, 0.f, 0.f};
    vf4 vc = p[(y << 7) | x];
    vf4 vl = (x > 0)      ? p[(y << 7) | (x - 1)] : z;
    vf4 vr = (x < PW - 1) ? p[(y << 7) | (x + 1)] : z;
    vf4 vu = (y > 0)      ? p[((y - 1) << 7) | x] : z;
    vf4 vd = (y < PH - 1) ? p[((y + 1) << 7) | x] : z;

    float c  = (vc.x + vc.y) + vc.z;   // .w is dead (poisoned ws) — never read
    float l  = (vl.x + vl.y) + vl.z;
    float r  = (vr.x + vr.y) + vr.z;
    float u  = (vu.x + vu.y) + vu.z;
    float dn = (vd.x + vd.y) + vd.z;

    float dl = c - l, dr = c - r, du = c - u, dd = c - dn;
    float s = (dl * dl + dr * dr) + (du * du + dd * dd);

#pragma unroll
    for (int off = 32; off > 0; off >>= 1)
        s += __shfl_down(s, off, 64);

    __shared__ float smem[4];
    int lane = threadIdx.x & 63;
    int wid  = threadIdx.x >> 6;
    if (lane == 0) smem[wid] = s;
    __syncthreads();
    if (threadIdx.x == 0)
        partials_out[blockIdx.x] = (smem[0] + smem[1]) + (smem[2] + smem[3]);
}

// Stage C: single block folds 2048 partials -> final mean (R0's proven tail).
__global__ __launch_bounds__(256) void spa_final_c(
    const float* __restrict__ partials, float* __restrict__ out)
{
    float s = 0.f;
#pragma unroll
    for (int i = 0; i < NBLK_RED / 256; ++i)
        s += partials[i * 256 + threadIdx.x];

#pragma unroll
    for (int off = 32; off > 0; off >>= 1)
        s += __shfl_down(s, off, 64);

    __shared__ float smem[4];
    int lane = threadIdx.x & 63;
    int wid  = threadIdx.x >> 6;
    if (lane == 0) smem[wid] = s;
    __syncthreads();
    if (threadIdx.x == 0)
        out[0] = ((smem[0] + smem[1]) + (smem[2] + smem[3])) * (1.0f / (float)NPOOL);
}

extern "C" void kernel_launch(void* const* d_in, const int* in_sizes, int n_in,
                              void* d_out, int out_size, void* d_ws, size_t ws_size,
                              hipStream_t stream) {
    const vf4* o4 = (const vf4*)d_in[0];
    const vf4* e4 = (const vf4*)d_in[1];
    float* out      = (float*)d_out;
    float* pooled4  = (float*)d_ws;                    // 8 MB: [32][128][128][4]
    float* bpartial = (float*)d_ws + 4 * NPOOL;        // + 8 KB

    spa_pool_a<<<NBLK_A, 256, 0, stream>>>(o4, e4, pooled4);
    spa_stencil_b<<<NBLK_RED, 256, 0, stream>>>((const vf4*)pooled4, bpartial);
    spa_final_c<<<1, 256, 0, stream>>>(bpartial, out);
}

// Round 7
// 197.616 us; speedup vs baseline: 1.1969x; 1.0165x over previous
//
#include <hip/hip_runtime.h>

// Problem constants (from reference): org/enh [32,3,512,512] fp32.
#define NB 32
#define NC 3
#define NH 512
#define NW 512
#define PH 128   // NH/4
#define PW 128   // NW/4
#define NPOOL  (NB * PH * PW)     // 524288 pooled elements
#define NPLANE (NB * NC)          // 96 (b,c) planes
#define PLANE_ELEMS (PH * PW)     // 16384 per partial plane
#define NITEMS (NPLANE * PLANE_ELEMS)  // 1,572,864 stage-A work items
#define NBLK_A 1024
#define ITEMS_A 6                 // 1024*256*6 == NITEMS exactly
#define STRIDE_A (NBLK_A * 256)   // 262144
#define NBLK_RED (NPOOL / 256)    // 2048

typedef float vf4 __attribute__((ext_vector_type(4)));

// item -> float4 base index in a [96][512][128] float4 layout:
// plane = item>>14, pooled row = (item>>7)&127 (covers image rows 4r..4r+3),
// x4 = item&127.
__device__ __forceinline__ int item_base(int item) {
    return ((item >> 14) << 16) + (((item >> 7) & 127) << 9) + (item & 127);
}

// Stage A: per-channel fused 4x4 avgpool of (org - enh), deep software
// pipeline. SESSION EVIDENCE (R0-R6): this exact form is the fastest of
// three structurally distinct stageA implementations (55-58 us, 3.66 TB/s
// effective read). The ceiling is per-CU outstanding-miss-slots (~64 lines
// x 128 B) / ~560 ns mixed L3/HBM latency — neither HBM (1.8/6.3 TB/s) nor
// L3 is saturated. One-shot blocks (scattered R1 / contiguous+LDS R2) pay
// full latency per block generation and land at 2.7 TB/s. Do not restructure.
__global__ __launch_bounds__(256) void stageA_pool_kernel(
    const vf4* __restrict__ o4, const vf4* __restrict__ e4,
    float* __restrict__ partial)
{
    int item = blockIdx.x * 256 + threadIdx.x;

    int base = item_base(item);
    vf4 oc0 = __builtin_nontemporal_load(o4 + base);
    vf4 oc1 = __builtin_nontemporal_load(o4 + base + 128);
    vf4 oc2 = __builtin_nontemporal_load(o4 + base + 256);
    vf4 oc3 = __builtin_nontemporal_load(o4 + base + 384);
    vf4 ec0 = __builtin_nontemporal_load(e4 + base);
    vf4 ec1 = __builtin_nontemporal_load(e4 + base + 128);
    vf4 ec2 = __builtin_nontemporal_load(e4 + base + 256);
    vf4 ec3 = __builtin_nontemporal_load(e4 + base + 384);

#pragma unroll
    for (int it = 0; it < ITEMS_A; ++it) {
        vf4 on0, on1, on2, on3, en0, en1, en2, en3;
        if (it < ITEMS_A - 1) {
            int nbase = item_base(item + STRIDE_A);
            on0 = __builtin_nontemporal_load(o4 + nbase);
            on1 = __builtin_nontemporal_load(o4 + nbase + 128);
            on2 = __builtin_nontemporal_load(o4 + nbase + 256);
            on3 = __builtin_nontemporal_load(o4 + nbase + 384);
            en0 = __builtin_nontemporal_load(e4 + nbase);
            en1 = __builtin_nontemporal_load(e4 + nbase + 128);
            en2 = __builtin_nontemporal_load(e4 + nbase + 256);
            en3 = __builtin_nontemporal_load(e4 + nbase + 384);
        }

        vf4 d = ((oc0 - ec0) + (oc1 - ec1)) + ((oc2 - ec2) + (oc3 - ec3));
        float v = (d.x + d.y) + (d.z + d.w);
        partial[item] = v * (1.0f / 48.0f);   // /3 channels /16 pool window

        if (it < ITEMS_A - 1) {
            oc0 = on0; oc1 = on1; oc2 = on2; oc3 = on3;
            ec0 = en0; ec1 = en1; ec2 = en2; ec3 = en3;
            item += STRIDE_A;
        }
    }
}

// Stage B: shift-difference sum-of-squares with inline channel-plane sum.
// pooled[b,y,x] = sum_c partial[(3b+c),y,x]; 6 MB working set, L2/L3-resident.
// Per-block partials to ws. SESSION EVIDENCE: same-address atomicAdd tail
// (R1/R5) costs +22-28 us (device-scope RMW storm on d_out); vec4-interleaved
// layout (R6) ties at best (stageA store scatter eats the tap savings).
// This plain form is the measured-best tail.
__global__ __launch_bounds__(256) void spa_reduce_kernel(
    const float* __restrict__ partial, float* __restrict__ partials_out)
{
    int idx = blockIdx.x * blockDim.x + threadIdx.x;
    int pw = idx & (PW - 1);
    int ph = (idx >> 7) & (PH - 1);
    int b  = idx >> 14;

    const float* p0 = partial + (b * 3 + 0) * PLANE_ELEMS;
    const float* p1 = partial + (b * 3 + 1) * PLANE_ELEMS;
    const float* p2 = partial + (b * 3 + 2) * PLANE_ELEMS;

    #define POOLED(y, x) (p0[(y) * PW + (x)] + p1[(y) * PW + (x)] + p2[(y) * PW + (x)])
    float c = POOLED(ph, pw);
    float l = (pw > 0)      ? POOLED(ph, pw - 1) : 0.f;
    float r = (pw < PW - 1) ? POOLED(ph, pw + 1) : 0.f;
    float u = (ph > 0)      ? POOLED(ph - 1, pw) : 0.f;
    float d = (ph < PH - 1) ? POOLED(ph + 1, pw) : 0.f;
    #undef POOLED

    float dl = c - l, dr = c - r, du = c - u, dd = c - d;
    float s = (dl * dl + dr * dr) + (du * du + dd * dd);

#pragma unroll
    for (int off = 32; off > 0; off >>= 1)
        s += __shfl_down(s, off, 64);

    __shared__ float smem[4];
    int lane = threadIdx.x & 63;
    int wid  = threadIdx.x >> 6;
    if (lane == 0) smem[wid] = s;
    __syncthreads();
    if (threadIdx.x == 0)
        partials_out[blockIdx.x] = (smem[0] + smem[1]) + (smem[2] + smem[3]);
}

// Stage C: single block folds 2048 partials -> final mean, writes d_out.
__global__ __launch_bounds__(256) void final_reduce_kernel(
    const float* __restrict__ partials, float* __restrict__ out)
{
    float s = 0.f;
#pragma unroll
    for (int i = 0; i < NBLK_RED / 256; ++i)
        s += partials[i * 256 + threadIdx.x];

#pragma unroll
    for (int off = 32; off > 0; off >>= 1)
        s += __shfl_down(s, off, 64);

    __shared__ float smem[4];
    int lane = threadIdx.x & 63;
    int wid  = threadIdx.x >> 6;
    if (lane == 0) smem[wid] = s;
    __syncthreads();
    if (threadIdx.x == 0)
        out[0] = ((smem[0] + smem[1]) + (smem[2] + smem[3])) * (1.0f / (float)NPOOL);
}

extern "C" void kernel_launch(void* const* d_in, const int* in_sizes, int n_in,
                              void* d_out, int out_size, void* d_ws, size_t ws_size,
                              hipStream_t stream) {
    const vf4* o4 = (const vf4*)d_in[0];
    const vf4* e4 = (const vf4*)d_in[1];
    float* out = (float*)d_out;
    float* partial      = (float*)d_ws;                 // 6 MB: [96][128][128]
    float* blockpartial = (float*)d_ws + NITEMS;        // + 8 KB

    stageA_pool_kernel<<<NBLK_A, 256, 0, stream>>>(o4, e4, partial);
    spa_reduce_kernel<<<NBLK_RED, 256, 0, stream>>>(partial, blockpartial);
    final_reduce_kernel<<<1, 256, 0, stream>>>(blockpartial, out);
}